// Round 5
// baseline (870.612 us; speedup 1.0000x reference)
//
#include <hip/hip_runtime.h>

// DynamicSparseScaledDotProductAttention on MI355X (gfx950)
// q,k,v: [32, 2048, 64] fp32; gate_w: [1,64]; gate_b: [1]
// outputs (tuple): out [32,2048,64] fp32, attn [32,2048,2048] fp32
//
// v6: break the vmcnt store/load coupling.
//  - v5 post-mortem: all pipes idle (~2400 cy/iter of waitcnt). vmcnt is
//    in-order and counts stores: each iteration's load-wait retired the
//    previous iteration's NT store acks (HBM write path). Fix: issue ALL
//    loads for the next stage BEFORE this stage's stores (ping-pong register
//    prefetch, manual 2x unroll) -> compiler derives vmcnt(N>0) waits that
//    never require store completion; loads get a full iteration of cover.
//  - True full-sector attn stores: row=lane>>3 (+8), col=(lane&7)*4 ->
//    each NT store instruction covers 8 rows x 128B contiguous (v5's mapping
//    still wrote half-sectors -> 700 vs 545MB WRITE).
//  - Pass 1: same 1-ahead K prefetch (pure-load pipeline).
// Kept (verified): gate-split, key-split flash, skewed pass-2 LDS transpose,
// per-wave Pool with osum alias, XCD-chunked swizzle, NT stores, 32-q blocks.
//
// MFMA mfma_f32_16x16x32_bf16 layouts (HW-verified per guide):
//   A-frag: lane holds A[m=lane&15][k=(lane>>4)*8 + j], j=0..7
//   B-frag: lane holds B[k=(lane>>4)*8+j][n=lane&15]
//   C/D   : lane holds D[row=(lane>>4)*4 + r][col=lane&15], r=0..3

typedef short bf16x8 __attribute__((ext_vector_type(8)));
typedef float f32x4  __attribute__((ext_vector_type(4)));

#define LSEQ 2048
#define DDIM 64
#define PB_STRIDE 36   // Pbuf row stride (f32)
#define OS_STRIDE 68   // osum row stride (f32)
#define POOLF 1168     // per-wave pool floats: >= 2*576 (Pbuf), >= 16*68 (osum)

#define MFMA16(A, B, C) __builtin_amdgcn_mfma_f32_16x16x32_bf16((A), (B), (C), 0, 0, 0)

__device__ __forceinline__ unsigned short f2bf(float x) {
    // round-to-nearest-even fp32 -> bf16
    unsigned int u = __float_as_uint(x);
    u += 0x7FFFu + ((u >> 16) & 1u);
    return (unsigned short)(u >> 16);
}

__device__ __forceinline__ unsigned int pk2f(float a, float b) {
    return (unsigned int)f2bf(a) | ((unsigned int)f2bf(b) << 16);
}

__device__ __forceinline__ unsigned int pk2u(unsigned short a, unsigned short b) {
    return (unsigned int)a | ((unsigned int)b << 16);
}

__device__ __forceinline__ float pick5(int jj, float e0, float e1, float e2,
                                       float e3, float e4) {
    float r = 0.f;
    r = (jj == 0) ? e0 : r;
    r = (jj == 1) ? e1 : r;
    r = (jj == 2) ? e2 : r;
    r = (jj == 3) ? e3 : r;
    r = (jj == 4) ? e4 : r;
    return r;
}

// ---------------- prep: K -> bf16 [bh][key][d]; V -> bf16 transposed [bh][d][key]
__global__ __launch_bounds__(256)
void dsa_prep(const float* __restrict__ K, const float* __restrict__ V,
              unsigned short* __restrict__ Kb, unsigned short* __restrict__ Vt)
{
    // XCD-chunked swizzle (nwg=1024, 8 XCDs): XCD x handles bh [4x, 4x+4)
    const int bx  = blockIdx.x;
    const int w   = ((bx & 7) << 7) + (bx >> 3);
    const int bh  = w >> 5;
    const int k0  = (w & 31) << 6;            // 64-key chunk
    const int tid = threadIdx.x;
    __shared__ unsigned short tileT[64][73];  // [d][key] (+pad)

    const int key = tid >> 2;                 // 0..63
    const int d0  = (tid & 3) << 4;           // 0,16,32,48
    const float* srcK = K + ((size_t)bh * LSEQ + k0 + key) * DDIM + d0;
    const float* srcV = V + ((size_t)bh * LSEQ + k0 + key) * DDIM + d0;
    {   // K: straight convert, 16 elems/thread, 2x16B stores
        uint4 w0, w1;
        w0.x = pk2f(srcK[0],  srcK[1]);  w0.y = pk2f(srcK[2],  srcK[3]);
        w0.z = pk2f(srcK[4],  srcK[5]);  w0.w = pk2f(srcK[6],  srcK[7]);
        w1.x = pk2f(srcK[8],  srcK[9]);  w1.y = pk2f(srcK[10], srcK[11]);
        w1.z = pk2f(srcK[12], srcK[13]); w1.w = pk2f(srcK[14], srcK[15]);
        unsigned short* dst = Kb + ((size_t)bh * LSEQ + k0 + key) * DDIM + d0;
        *(uint4*)(dst)     = w0;
        *(uint4*)(dst + 8) = w1;
    }
    #pragma unroll
    for (int j = 0; j < 16; ++j) tileT[d0 + j][key] = f2bf(srcV[j]);
    __syncthreads();
    {   // V: write transposed rows coalesced
        const int d   = tid >> 2;
        const int kk0 = (tid & 3) << 4;
        uint4 w0, w1;
        w0.x = pk2u(tileT[d][kk0 + 0],  tileT[d][kk0 + 1]);
        w0.y = pk2u(tileT[d][kk0 + 2],  tileT[d][kk0 + 3]);
        w0.z = pk2u(tileT[d][kk0 + 4],  tileT[d][kk0 + 5]);
        w0.w = pk2u(tileT[d][kk0 + 6],  tileT[d][kk0 + 7]);
        w1.x = pk2u(tileT[d][kk0 + 8],  tileT[d][kk0 + 9]);
        w1.y = pk2u(tileT[d][kk0 + 10], tileT[d][kk0 + 11]);
        w1.z = pk2u(tileT[d][kk0 + 12], tileT[d][kk0 + 13]);
        w1.w = pk2u(tileT[d][kk0 + 14], tileT[d][kk0 + 15]);
        unsigned short* dst = Vt + (size_t)bh * DDIM * LSEQ + (size_t)d * LSEQ + k0 + kk0;
        *(uint4*)(dst)     = w0;
        *(uint4*)(dst + 8) = w1;
    }
}

// ---------------- main: 32 queries per block, 2048 blocks
__global__ __launch_bounds__(256)
void dsa_main(const float* __restrict__ Q,
              const unsigned short* __restrict__ Kb,   // bf16 [bh][key][d]
              const unsigned short* __restrict__ Vt,   // bf16 [bh][d][key]
              const float* __restrict__ K32,
              const float* __restrict__ V32,
              const float* __restrict__ GW,
              const float* __restrict__ GB,
              float* __restrict__ OUT,
              float* __restrict__ ATT)
{
    __shared__ float Pool[4][POOLF];
    __shared__ float dsum[4][16];   // per-wave partial denominators
    __shared__ int   sidx[32];      // full rows first, then window rows
    __shared__ int   gShared;

    // XCD-chunked swizzle (nwg=2048, 8 XCDs): XCD x handles bh [4x, 4x+4)
    const int bx   = blockIdx.x;
    const int w    = ((bx & 7) << 8) + (bx >> 3);
    const int bh   = w >> 6;
    const int q0   = (w & 63) << 5;   // 32-query tile
    const int tid  = threadIdx.x;
    const int wave = tid >> 6;
    const int lane = tid & 63;
    const int m16  = lane & 15;
    const int quad = lane >> 4;

    const float* qb = Q + ((size_t)bh * LSEQ + q0) * DDIM;

    // ---- gate (exact fp32: sigmoid(x)>0.5 <=> x>0) + ballot sort, wave 0 ----
    if (wave == 0) {
        const int row = lane & 31;
        const float* qr = qb + row * DDIM;
        float a = 0.f;
        #pragma unroll 8
        for (int d = 0; d < DDIM; ++d) a += qr[d] * GW[d];
        a += GB[0];
        const bool gt = (lane < 32) && (a > 0.f);
        const unsigned long long b = __ballot(gt);
        const int below = __popcll(b & ((1ull << lane) - 1ull));
        const int gg    = __popcll(b);
        if (lane < 32) {
            const int pos = gt ? below : (gg + (lane - below));
            sidx[pos] = lane;
        }
        if (lane == 0) gShared = gg;
    }
    __syncthreads();
    const int g = gShared;
    const int T = (g + 15) >> 4;   // full 16-row tiles (0..2)

    const unsigned short* kbb = Kb + (size_t)bh * LSEQ * DDIM;
    const unsigned short* vtb = Vt + (size_t)bh * DDIM * LSEQ;
    const int kbase = wave << 9;   // this wave's 512-key slice

    // full-sector store mapping: 8 lanes cover one row's 128B contiguously
    const int srowA = lane >> 3;          // 0..7 (s1 handles +8)
    const int scol3 = (lane & 7) << 2;    // 0,4,...,28 (floats)

    #define LOADK(P, KT) {                                                    \
        const unsigned short* kp_ = kp0 + (size_t)((KT) * 32) * DDIM;         \
        P##0 = *(const bf16x8*)(kp_);                                         \
        P##1 = *(const bf16x8*)(kp_ + 32);                                    \
        P##2 = *(const bf16x8*)(kp_ + 16 * DDIM);                             \
        P##3 = *(const bf16x8*)(kp_ + 16 * DDIM + 32);                        \
    }
    #define LOADV(P, KT) {                                                    \
        const unsigned short* vp_ = vp0 + (KT) * 32;                          \
        P##0 = *(const bf16x8*)(vp_);                                         \
        P##1 = *(const bf16x8*)(vp_ + 16 * LSEQ);                             \
        P##2 = *(const bf16x8*)(vp_ + 32 * LSEQ);                             \
        P##3 = *(const bf16x8*)(vp_ + 48 * LSEQ);                             \
    }

    // =================== full tiles: all 4 waves cooperate (key-split) ============
    for (int t = 0; t < T; ++t) {
        const int  myIdx = (t << 4) + m16;
        const bool valid = myIdx < g;
        const int  srow  = sidx[valid ? myIdx : (g - 1)];

        // attn-store rows for the full-sector mapping
        const int  rA   = (t << 4) + srowA;
        const bool v2a  = rA < g;
        const bool v2b  = (rA + 8) < g;
        float* ap2a = ATT + ((size_t)(bh * LSEQ + q0 + sidx[v2a ? rA : (g - 1)])) * LSEQ
                          + kbase + scol3;
        float* ap2b = ATT + ((size_t)(bh * LSEQ + q0 + sidx[v2b ? (rA + 8) : (g - 1)])) * LSEQ
                          + kbase + scol3;

        // per-lane Q A-frags for this tile
        bf16x8 qfrag[2];
        {
            const float* qr = qb + srow * DDIM + (quad << 3);
            #pragma unroll
            for (int db = 0; db < 2; ++db) {
                const float* p = qr + db * 32;
                bf16x8 f;
                #pragma unroll
                for (int j = 0; j < 8; ++j) f[j] = (short)f2bf(p[j]);
                qfrag[db] = f;
            }
        }

        const unsigned short* kp0 = kbb + (size_t)(kbase + m16) * DDIM + (quad << 3);
        const unsigned short* vp0 = vtb + (size_t)m16 * LSEQ + kbase + (quad << 3);

        // ---- pass 1: partial denominators, 1-ahead K prefetch ----
        float lsum[4] = {0.f, 0.f, 0.f, 0.f};
        bf16x8 ka0, ka1, ka2, ka3, kb0, kb1, kb2, kb3;

        #define P1STEP(KC) {                                                  \
            f32x4 a0 = {0.f,0.f,0.f,0.f}, a1 = {0.f,0.f,0.f,0.f};             \
            a0 = MFMA16(qfrag[0], KC##0, a0);                                 \
            a0 = MFMA16(qfrag[1], KC##1, a0);                                 \
            a1 = MFMA16(qfrag[0], KC##2, a1);                                 \
            a1 = MFMA16(qfrag[1], KC##3, a1);                                 \
            _Pragma("unroll")                                                 \
            for (int r = 0; r < 4; ++r)                                       \
                lsum[r] += __expf(a0[r] * 0.125f) + __expf(a1[r] * 0.125f);   \
        }

        LOADK(ka, 0)
        for (int kt = 0; kt < 14; kt += 2) {
            LOADK(kb, kt + 1)
            P1STEP(ka)
            LOADK(ka, kt + 2)
            P1STEP(kb)
        }
        LOADK(kb, 15)
        P1STEP(ka)
        P1STEP(kb)
        #undef P1STEP

        #pragma unroll
        for (int r = 0; r < 4; ++r) {
            float x = lsum[r];
            x += __shfl_xor(x, 1); x += __shfl_xor(x, 2);
            x += __shfl_xor(x, 4); x += __shfl_xor(x, 8);
            if (m16 == 0) dsum[wave][(quad << 2) + r] = x;
        }
        __syncthreads();   // A: denominators complete

        float inv[4];
        #pragma unroll
        for (int r = 0; r < 4; ++r) {
            const int rr = (quad << 2) + r;
            inv[r] = 1.0f / (dsum[0][rr] + dsum[1][rr] + dsum[2][rr] + dsum[3][rr]);
        }

        // ---- pass 2: pipelined (loads for stage kt issued BEFORE stores of kt) ----
        f32x4 oacc0 = {0.f,0.f,0.f,0.f}, oacc1 = {0.f,0.f,0.f,0.f};
        f32x4 oacc2 = {0.f,0.f,0.f,0.f}, oacc3 = {0.f,0.f,0.f,0.f};
        bf16x8 va0, va1, va2, va3, vb0, vb1, vb2, vb3;

        #define WRITEP(KT, A0, A1) {                                          \
            float* pw_ = &Pool[wave][((KT) & 1) * 576];                       \
            _Pragma("unroll")                                                 \
            for (int r = 0; r < 4; ++r) {                                     \
                const int prow = (quad << 2) + r;                             \
                pw_[prow * PB_STRIDE + m16]      = __expf(A0[r]*0.125f)*inv[r]; \
                pw_[prow * PB_STRIDE + 16 + m16] = __expf(A1[r]*0.125f)*inv[r]; \
            }                                                                 \
        }

        // STAGE kt: issue K(kt+1),V(kt); read P(kt-1); QK(kt); write P(kt);
        //           store attn(kt-1); PV(kt-1) with VP.
        #define STAGE(KT, KC, KN, VI, VP, DOLK) {                             \
            if (DOLK) LOADK(KN, ((KT) + 1) & 15)                              \
            LOADV(VI, KT)                                                     \
            const float* pb_  = &Pool[wave][(((KT) - 1) & 1) * 576];          \
            const float* prd_ = pb_ + m16 * PB_STRIDE + (quad << 3);          \
            f32x4 p0 = *(const f32x4*)(prd_);                                 \
            f32x4 p1 = *(const f32x4*)(prd_ + 4);                             \
            f32x4 s0 = *(const f32x4*)(pb_ + srowA * PB_STRIDE + scol3);      \
            f32x4 s1 = *(const f32x4*)(pb_ + (srowA + 8) * PB_STRIDE + scol3);\
            f32x4 a0 = {0.f,0.f,0.f,0.f}, a1 = {0.f,0.f,0.f,0.f};             \
            a0 = MFMA16(qfrag[0], KC##0, a0);                                 \
            a0 = MFMA16(qfrag[1], KC##1, a0);                                 \
            a1 = MFMA16(qfrag[0], KC##2, a1);                                 \
            a1 = MFMA16(qfrag[1], KC##3, a1);                                 \
            WRITEP(KT, a0, a1)                                                \
            if (v2a) __builtin_nontemporal_store(s0, (f32x4*)(ap2a + ((KT)-1)*32)); \
            if (v2b) __builtin_nontemporal_store(s1, (f32x4*)(ap2b + ((KT)-1)*32)); \
            bf16x8 pf;                                                        \
            _Pragma("unroll")                                                 \
            for (int j = 0; j < 4; ++j) {                                     \
                pf[j]     = (short)f2bf(p0[j]);                               \
                pf[4 + j] = (short)f2bf(p1[j]);                               \
            }                                                                 \
            oacc0 = MFMA16(pf, VP##0, oacc0);                                 \
            oacc1 = MFMA16(pf, VP##1, oacc1);                                 \
            oacc2 = MFMA16(pf, VP##2, oacc2);                                 \
            oacc3 = MFMA16(pf, VP##3, oacc3);                                 \
        }

        LOADK(ka, 0)
        {   // stage 0: compute P(0) only
            LOADK(kb, 1)
            LOADV(va, 0)
            f32x4 a0 = {0.f,0.f,0.f,0.f}, a1 = {0.f,0.f,0.f,0.f};
            a0 = MFMA16(qfrag[0], ka0, a0);
            a0 = MFMA16(qfrag[1], ka1, a0);
            a1 = MFMA16(qfrag[0], ka2, a1);
            a1 = MFMA16(qfrag[1], ka3, a1);
            WRITEP(0, a0, a1)
        }
        for (int kt = 1; kt < 15; kt += 2) {
            STAGE(kt,     kb, ka, vb, va, 1)
            STAGE(kt + 1, ka, kb, va, vb, 1)
        }
        STAGE(15, kb, ka, vb, va, 0)
        {   // stage 16: consume P(15)
            const float* pb_  = &Pool[wave][576];
            const float* prd_ = pb_ + m16 * PB_STRIDE + (quad << 3);
            f32x4 p0 = *(const f32x4*)(prd_);
            f32x4 p1 = *(const f32x4*)(prd_ + 4);
            f32x4 s0 = *(const f32x4*)(pb_ + srowA * PB_STRIDE + scol3);
            f32x4 s1 = *(const f32x4*)(pb_ + (srowA + 8) * PB_STRIDE + scol3);
            if (v2a) __builtin_nontemporal_store(s0, (f32x4*)(ap2a + 15 * 32));
            if (v2b) __builtin_nontemporal_store(s1, (f32x4*)(ap2b + 15 * 32));
            bf16x8 pf;
            #pragma unroll
            for (int j = 0; j < 4; ++j) {
                pf[j]     = (short)f2bf(p0[j]);
                pf[4 + j] = (short)f2bf(p1[j]);
            }
            oacc0 = MFMA16(pf, vb0, oacc0);
            oacc1 = MFMA16(pf, vb1, oacc1);
            oacc2 = MFMA16(pf, vb2, oacc2);
            oacc3 = MFMA16(pf, vb3, oacc3);
        }
        #undef STAGE
        #undef WRITEP

        // partial O -> Pool (aliases Pbuf; this wave's Pbuf reads are done)
        #pragma unroll
        for (int r = 0; r < 4; ++r) {
            const int prow = (quad << 2) + r;
            float* ow = &Pool[wave][prow * OS_STRIDE];
            ow[m16]      = oacc0[r];
            ow[16 + m16] = oacc1[r];
            ow[32 + m16] = oacc2[r];
            ow[48 + m16] = oacc3[r];
        }
        __syncthreads();   // B: partials complete

        // cross-wave O reduce + coalesced OUT store
        #pragma unroll
        for (int rep = 0; rep < 4; ++rep) {
            const int idx = rep * 256 + tid;      // 0..1023
            const int row = idx >> 6;             // 0..15
            const int col = idx & 63;
            const int gi  = (t << 4) + row;
            if (gi < g) {
                const float s = Pool[0][row * OS_STRIDE + col]
                              + Pool[1][row * OS_STRIDE + col]
                              + Pool[2][row * OS_STRIDE + col]
                              + Pool[3][row * OS_STRIDE + col];
                __builtin_nontemporal_store(
                    s, &OUT[((size_t)(bh * LSEQ + q0 + sidx[gi])) * DDIM + col]);
            }
        }
        __syncthreads();   // C: protect Pool/dsum reuse next tile
    }
    #undef LOADK
    #undef LOADV

    // =================== window rows (gate off): exact fp32, 5-key softmax =========
    const int nw = 32 - g;
    for (int ii = wave; ii < nw; ii += 4) {
        const int row = sidx[g + ii];
        const int i   = q0 + row;                       // global query index
        const float qd = qb[row * DDIM + lane];         // d = lane

        float e[5];
        float denom = 0.f;
        #pragma unroll
        for (int jj = 0; jj < 5; ++jj) {
            const int  j  = i - 2 + jj;
            const bool ok = (j >= 0) && (j < LSEQ);
            const int  jc = ok ? j : 0;
            float tt = qd * K32[((size_t)bh * LSEQ + jc) * DDIM + lane];
            tt += __shfl_xor(tt, 1);  tt += __shfl_xor(tt, 2);
            tt += __shfl_xor(tt, 4);  tt += __shfl_xor(tt, 8);
            tt += __shfl_xor(tt, 16); tt += __shfl_xor(tt, 32);
            const float ee = ok ? __expf(tt * 0.125f) : 0.f;
            e[jj] = ee;
            denom += ee;
        }
        const float invd = 1.f / denom;
        #pragma unroll
        for (int jj = 0; jj < 5; ++jj) e[jj] *= invd;

        // out row: o[d] = sum_j p_j * V[j][d]  (lane = d, coalesced)
        float o = 0.f;
        #pragma unroll
        for (int jj = 0; jj < 5; ++jj) {
            const int  j  = i - 2 + jj;
            const int  jc = (j >= 0 && j < LSEQ) ? j : 0;
            o += e[jj] * V32[((size_t)bh * LSEQ + jc) * DDIM + lane];
        }
        __builtin_nontemporal_store(o, &OUT[((size_t)(bh * LSEQ + i)) * DDIM + lane]);

        // attn row: zeros with the <=5 window values merged in-register
        float* ar = ATT + ((size_t)(bh * LSEQ + i)) * LSEQ;
        const int jlo = i - 2;
        #pragma unroll
        for (int it = 0; it < 8; ++it) {
            const int c = (it << 8) + (lane << 2);
            f32x4 z = {0.f, 0.f, 0.f, 0.f};
            if (c + 3 >= jlo && c <= jlo + 4) {
                #pragma unroll
                for (int t4 = 0; t4 < 4; ++t4)
                    z[t4] = pick5(c + t4 - jlo, e[0], e[1], e[2], e[3], e[4]);
            }
            __builtin_nontemporal_store(z, (f32x4*)(ar + c));
        }
    }
}

extern "C" void kernel_launch(void* const* d_in, const int* in_sizes, int n_in,
                              void* d_out, int out_size, void* d_ws, size_t ws_size,
                              hipStream_t stream) {
    const float* q  = (const float*)d_in[0];
    const float* k  = (const float*)d_in[1];
    const float* v  = (const float*)d_in[2];
    const float* gw = (const float*)d_in[3];
    const float* gb = (const float*)d_in[4];

    float* out  = (float*)d_out;                      // [32,2048,64]
    float* attn = out + (size_t)32 * 2048 * 64;       // [32,2048,2048]

    // workspace: Kb bf16 [32][2048][64] (8MB) + Vt bf16 [32][64][2048] (8MB)
    unsigned short* Kb = (unsigned short*)d_ws;
    unsigned short* Vt = Kb + (size_t)32 * 2048 * 64;

    dim3 block(256);
    dsa_prep<<<dim3(1024), block, 0, stream>>>(k, v, Kb, Vt);
    dsa_main<<<dim3(2048), block, 0, stream>>>(q, Kb, Vt, k, v, gw, gb, out, attn);
}

// Round 6
// 712.587 us; speedup vs baseline: 1.2218x; 1.2218x over previous
//
#include <hip/hip_runtime.h>

// DynamicSparseScaledDotProductAttention on MI355X (gfx950)
// q,k,v: [32, 2048, 64] fp32; gate_w: [1,64]; gate_b: [1]
// outputs (tuple): out [32,2048,64] fp32, attn [32,2048,2048] fp32
//
// v7: global_load_lds staged pass 2 (prefetch depth without VGPR cost).
//  - v6 post-mortem: WRITE fixed at ideal 540MB, FETCH at 32MB floor, but
//    register prefetch pushed VGPR to 140 -> occupancy bucket halved. All
//    pipes <17%: pure unhidden latency. Fix: K/V tiles staged direct-to-LDS
//    (double-buffered, 64-key tiles, XOR-swizzled source + swizzled ds_read),
//    raw s_barrier + inline vmcnt(0) per tile. VGPR ~100 -> 3 blocks/CU.
//  - Uniform compute: ALL 32 rows get full attention (MFMA is ~4% busy;
//    gate sparsity only predicates the stores). No sort-driven imbalance.
//    Waves = 2 q-tiles x 2 key-halves; denominators/O combined via LDS.
//  - Pass 1 keeps v6's proven register pipeline (no stores -> no coupling).
//
// MFMA mfma_f32_16x16x32_bf16 layouts (HW-verified per guide):
//   A-frag: lane holds A[m=lane&15][k=(lane>>4)*8 + j], j=0..7
//   B-frag: lane holds B[k=(lane>>4)*8+j][n=lane&15]
//   C/D   : lane holds D[row=(lane>>4)*4 + r][col=lane&15], r=0..3

typedef short bf16x8 __attribute__((ext_vector_type(8)));
typedef float f32x4  __attribute__((ext_vector_type(4)));

#define LSEQ 2048
#define DDIM 64
#define PB_STRIDE 36   // Pls row stride (f32); 144B rows, 16B-aligned
#define OS_STRIDE 68   // osum row stride (f32)

#define MFMA16(A, B, C) __builtin_amdgcn_mfma_f32_16x16x32_bf16((A), (B), (C), 0, 0, 0)

#define GLOAD_LDS16(GP, LP)                                                       \
    __builtin_amdgcn_global_load_lds(                                             \
        (const __attribute__((address_space(1))) unsigned int*)(GP),              \
        (__attribute__((address_space(3))) unsigned int*)(LP), 16, 0, 0)

__device__ __forceinline__ unsigned short f2bf(float x) {
    unsigned int u = __float_as_uint(x);
    u += 0x7FFFu + ((u >> 16) & 1u);
    return (unsigned short)(u >> 16);
}

__device__ __forceinline__ unsigned int pk2f(float a, float b) {
    return (unsigned int)f2bf(a) | ((unsigned int)f2bf(b) << 16);
}

__device__ __forceinline__ unsigned int pk2u(unsigned short a, unsigned short b) {
    return (unsigned int)a | ((unsigned int)b << 16);
}

__device__ __forceinline__ float pick5(int jj, float e0, float e1, float e2,
                                       float e3, float e4) {
    float r = 0.f;
    r = (jj == 0) ? e0 : r;
    r = (jj == 1) ? e1 : r;
    r = (jj == 2) ? e2 : r;
    r = (jj == 3) ? e3 : r;
    r = (jj == 4) ? e4 : r;
    return r;
}

// ---------------- prep: K -> bf16 [bh][key][d]; V -> bf16 transposed [bh][d][key]
__global__ __launch_bounds__(256)
void dsa_prep(const float* __restrict__ K, const float* __restrict__ V,
              unsigned short* __restrict__ Kb, unsigned short* __restrict__ Vt)
{
    const int bx  = blockIdx.x;
    const int w   = ((bx & 7) << 7) + (bx >> 3);   // XCD-chunked
    const int bh  = w >> 5;
    const int k0  = (w & 31) << 6;
    const int tid = threadIdx.x;
    __shared__ unsigned short tileT[64][73];

    const int key = tid >> 2;
    const int d0  = (tid & 3) << 4;
    const float* srcK = K + ((size_t)bh * LSEQ + k0 + key) * DDIM + d0;
    const float* srcV = V + ((size_t)bh * LSEQ + k0 + key) * DDIM + d0;
    {
        uint4 w0, w1;
        w0.x = pk2f(srcK[0],  srcK[1]);  w0.y = pk2f(srcK[2],  srcK[3]);
        w0.z = pk2f(srcK[4],  srcK[5]);  w0.w = pk2f(srcK[6],  srcK[7]);
        w1.x = pk2f(srcK[8],  srcK[9]);  w1.y = pk2f(srcK[10], srcK[11]);
        w1.z = pk2f(srcK[12], srcK[13]); w1.w = pk2f(srcK[14], srcK[15]);
        unsigned short* dst = Kb + ((size_t)bh * LSEQ + k0 + key) * DDIM + d0;
        *(uint4*)(dst)     = w0;
        *(uint4*)(dst + 8) = w1;
    }
    #pragma unroll
    for (int j = 0; j < 16; ++j) tileT[d0 + j][key] = f2bf(srcV[j]);
    __syncthreads();
    {
        const int d   = tid >> 2;
        const int kk0 = (tid & 3) << 4;
        uint4 w0, w1;
        w0.x = pk2u(tileT[d][kk0 + 0],  tileT[d][kk0 + 1]);
        w0.y = pk2u(tileT[d][kk0 + 2],  tileT[d][kk0 + 3]);
        w0.z = pk2u(tileT[d][kk0 + 4],  tileT[d][kk0 + 5]);
        w0.w = pk2u(tileT[d][kk0 + 6],  tileT[d][kk0 + 7]);
        w1.x = pk2u(tileT[d][kk0 + 8],  tileT[d][kk0 + 9]);
        w1.y = pk2u(tileT[d][kk0 + 10], tileT[d][kk0 + 11]);
        w1.z = pk2u(tileT[d][kk0 + 12], tileT[d][kk0 + 13]);
        w1.w = pk2u(tileT[d][kk0 + 14], tileT[d][kk0 + 15]);
        unsigned short* dst = Vt + (size_t)bh * DDIM * LSEQ + (size_t)d * LSEQ + k0 + kk0;
        *(uint4*)(dst)     = w0;
        *(uint4*)(dst + 8) = w1;
    }
}

// ---------------- main: 32 queries per block, 2048 blocks
__global__ __launch_bounds__(256)
void dsa_main(const float* __restrict__ Q,
              const unsigned short* __restrict__ Kb,   // bf16 [bh][key][d]
              const unsigned short* __restrict__ Vt,   // bf16 [bh][d][key]
              const float* __restrict__ K32,
              const float* __restrict__ V32,
              const float* __restrict__ GW,
              const float* __restrict__ GB,
              float* __restrict__ OUT,
              float* __restrict__ ATT)
{
    __shared__ unsigned short Kls[2][64 * 64];   // 16KB staged K (dbuf, swizzled)
    __shared__ unsigned short Vls[2][64 * 64];   // 16KB staged V (dbuf, swizzled)
    __shared__ float Pls[4][16 * PB_STRIDE];     // per-wave P tile (16q x 32k)
    __shared__ float dsum[4][16];
    __shared__ int   sidx[32];
    __shared__ int   gShared;
    __shared__ unsigned int gmaskS;

    const int bx   = blockIdx.x;
    const int w    = ((bx & 7) << 8) + (bx >> 3);   // XCD-chunked
    const int bh   = w >> 6;
    const int q0   = (w & 63) << 5;
    const int tid  = threadIdx.x;
    const int wave = tid >> 6;
    const int lane = tid & 63;
    const int m16  = lane & 15;
    const int quad = lane >> 4;
    const int qt   = wave >> 1;   // q-tile 0/1
    const int kh   = wave & 1;    // key-half 0/1

    const float* qb = Q + ((size_t)bh * LSEQ + q0) * DDIM;

    // ---- gate (exact fp32) + mask + window-row enumeration ----
    if (wave == 0) {
        const int row = lane & 31;
        const float* qr = qb + row * DDIM;
        float a = 0.f;
        #pragma unroll 8
        for (int d = 0; d < DDIM; ++d) a += qr[d] * GW[d];
        a += GB[0];
        const bool gt = (lane < 32) && (a > 0.f);
        const unsigned long long b = __ballot(gt);
        const int below = __popcll(b & ((1ull << lane) - 1ull));
        const int gg    = __popcll(b);
        if (lane < 32) {
            const int pos = gt ? below : (gg + (lane - below));
            sidx[pos] = lane;
        }
        if (lane == 0) { gShared = gg; gmaskS = (unsigned int)b; }
    }
    __syncthreads();
    const int g = gShared;
    const unsigned int gmask = gmaskS;

    const unsigned short* kbb = Kb + (size_t)bh * LSEQ * DDIM;
    const unsigned short* vtb = Vt + (size_t)bh * DDIM * LSEQ;

    // Q A-frags: rows qt*16 + m16 (natural order, all rows computed)
    bf16x8 qfrag[2];
    {
        const float* qr = qb + ((qt << 4) + m16) * DDIM + (quad << 3);
        #pragma unroll
        for (int db = 0; db < 2; ++db) {
            const float* p = qr + db * 32;
            bf16x8 f;
            #pragma unroll
            for (int j = 0; j < 8; ++j) f[j] = (short)f2bf(p[j]);
            qfrag[db] = f;
        }
    }

    // ================= pass 1: denominators (register pipeline, v6-style) =========
    // wave covers keys [kh*1024, kh*1024+1024) for its q-tile
    {
        const unsigned short* kp0 = kbb + (size_t)((kh << 10) + m16) * DDIM + (quad << 3);
        float lsum[4] = {0.f, 0.f, 0.f, 0.f};
        bf16x8 ka0, ka1, ka2, ka3, kb0, kb1, kb2, kb3;

        #define LOADK1(P, KT) {                                               \
            const unsigned short* kp_ = kp0 + (size_t)((KT) * 32) * DDIM;     \
            P##0 = *(const bf16x8*)(kp_);                                     \
            P##1 = *(const bf16x8*)(kp_ + 32);                                \
            P##2 = *(const bf16x8*)(kp_ + 16 * DDIM);                         \
            P##3 = *(const bf16x8*)(kp_ + 16 * DDIM + 32);                    \
        }
        #define P1STEP(KC) {                                                  \
            f32x4 a0 = {0.f,0.f,0.f,0.f}, a1 = {0.f,0.f,0.f,0.f};             \
            a0 = MFMA16(qfrag[0], KC##0, a0);                                 \
            a0 = MFMA16(qfrag[1], KC##1, a0);                                 \
            a1 = MFMA16(qfrag[0], KC##2, a1);                                 \
            a1 = MFMA16(qfrag[1], KC##3, a1);                                 \
            _Pragma("unroll")                                                 \
            for (int r = 0; r < 4; ++r)                                       \
                lsum[r] += __expf(a0[r] * 0.125f) + __expf(a1[r] * 0.125f);   \
        }

        LOADK1(ka, 0)
        for (int kt = 0; kt < 30; kt += 2) {
            LOADK1(kb, kt + 1)
            P1STEP(ka)
            LOADK1(ka, kt + 2)
            P1STEP(kb)
        }
        LOADK1(kb, 31)
        P1STEP(ka)
        P1STEP(kb)
        #undef P1STEP
        #undef LOADK1

        #pragma unroll
        for (int r = 0; r < 4; ++r) {
            float x = lsum[r];
            x += __shfl_xor(x, 1); x += __shfl_xor(x, 2);
            x += __shfl_xor(x, 4); x += __shfl_xor(x, 8);
            if (m16 == 0) dsum[wave][(quad << 2) + r] = x;
        }
    }
    __syncthreads();

    float inv[4];
    #pragma unroll
    for (int r = 0; r < 4; ++r) {
        const int rr = (quad << 2) + r;
        inv[r] = 1.0f / (dsum[qt * 2][rr] + dsum[qt * 2 + 1][rr]);
    }

    // ================= pass 2: LDS-staged 64-key tiles ============================
    // staging geometry: 8 chunks of 1KB per tile (K and V each); wave owns 2 chunks.
    const int a_ = lane >> 3;                  // 0..7
    const int b_ = lane & 7;                   // 0..7
    const int lanepart = ((a_ ^ b_) << 4);     // XOR-swizzled 16B slot in 128B row
    const int c0 = wave * 2, c1 = wave * 2 + 1;
    const char* kbbB = (const char*)kbb;
    const char* vtbB = (const char*)vtb;

    #define STAGE2(TT, BUF) {                                                     \
        GLOAD_LDS16(kbbB + (size_t)(TT) * 8192 + ((c0 * 8 + a_) << 7) + lanepart, \
                    (char*)Kls[BUF] + c0 * 1024);                                 \
        GLOAD_LDS16(kbbB + (size_t)(TT) * 8192 + ((c1 * 8 + a_) << 7) + lanepart, \
                    (char*)Kls[BUF] + c1 * 1024);                                 \
        GLOAD_LDS16(vtbB + (size_t)(c0 * 8 + a_) * 4096 + (TT) * 128 + lanepart,  \
                    (char*)Vls[BUF] + c0 * 1024);                                 \
        GLOAD_LDS16(vtbB + (size_t)(c1 * 8 + a_) * 4096 + (TT) * 128 + lanepart,  \
                    (char*)Vls[BUF] + c1 * 1024);                                 \
    }

    // swizzled ds_read addresses (row&7 == m16&7 for both K and V reads)
    const int kswz = (m16 & 7) << 4;
    #define KADDR(NT, DB) (((((kh << 5) + ((NT) << 4) + m16) << 7) + (DB) * 64 + (quad << 4)) ^ kswz)
    #define VADDR(DT)     (((((DT) * 16 + m16) << 7) + (kh << 6) + (quad << 4)) ^ kswz)

    // full-sector attn-store mapping (v6-proven: WRITE = ideal 540MB)
    const int srowA = lane >> 3;
    const int scol  = (lane & 7) << 2;
    const int qrowA = (qt << 4) + srowA;
    const bool gA = (gmask >> qrowA) & 1u;
    const bool gB = (gmask >> (qrowA + 8)) & 1u;
    float* apA = ATT + ((size_t)(bh * LSEQ + q0 + qrowA)) * LSEQ + (kh << 5) + scol;
    float* apB = ATT + ((size_t)(bh * LSEQ + q0 + qrowA + 8)) * LSEQ + (kh << 5) + scol;

    #define PSTORE(TT) {                                                          \
        f32x4 s0 = *(const f32x4*)(Pls[wave] + srowA * PB_STRIDE + scol);         \
        f32x4 s1 = *(const f32x4*)(Pls[wave] + (srowA + 8) * PB_STRIDE + scol);   \
        if (gA) __builtin_nontemporal_store(s0, (f32x4*)(apA + (TT) * 64));       \
        if (gB) __builtin_nontemporal_store(s1, (f32x4*)(apB + (TT) * 64));       \
    }

    f32x4 oacc0 = {0.f,0.f,0.f,0.f}, oacc1 = {0.f,0.f,0.f,0.f};
    f32x4 oacc2 = {0.f,0.f,0.f,0.f}, oacc3 = {0.f,0.f,0.f,0.f};

    #define TILE2(BUF) {                                                          \
        const char* kb_ = (const char*)Kls[BUF];                                  \
        const char* vb_ = (const char*)Vls[BUF];                                  \
        bf16x8 kf00 = *(const bf16x8*)(kb_ + KADDR(0, 0));                        \
        bf16x8 kf01 = *(const bf16x8*)(kb_ + KADDR(0, 1));                        \
        bf16x8 kf10 = *(const bf16x8*)(kb_ + KADDR(1, 0));                        \
        bf16x8 kf11 = *(const bf16x8*)(kb_ + KADDR(1, 1));                        \
        f32x4 a0 = {0.f,0.f,0.f,0.f}, a1 = {0.f,0.f,0.f,0.f};                     \
        a0 = MFMA16(qfrag[0], kf00, a0);                                          \
        a0 = MFMA16(qfrag[1], kf01, a0);                                          \
        a1 = MFMA16(qfrag[0], kf10, a1);                                          \
        a1 = MFMA16(qfrag[1], kf11, a1);                                          \
        float* pw_ = Pls[wave];                                                   \
        _Pragma("unroll")                                                         \
        for (int r = 0; r < 4; ++r) {                                             \
            const int prow = (quad << 2) + r;                                     \
            pw_[prow * PB_STRIDE + m16]      = __expf(a0[r] * 0.125f) * inv[r];   \
            pw_[prow * PB_STRIDE + 16 + m16] = __expf(a1[r] * 0.125f) * inv[r];   \
        }                                                                         \
        const float* prd_ = Pls[wave] + m16 * PB_STRIDE + (quad << 3);            \
        f32x4 p0 = *(const f32x4*)(prd_);                                         \
        f32x4 p1 = *(const f32x4*)(prd_ + 4);                                     \
        bf16x8 pf;                                                                \
        _Pragma("unroll")                                                         \
        for (int j = 0; j < 4; ++j) {                                             \
            pf[j]     = (short)f2bf(p0[j]);                                       \
            pf[4 + j] = (short)f2bf(p1[j]);                                       \
        }                                                                         \
        bf16x8 vf0 = *(const bf16x8*)(vb_ + VADDR(0));                            \
        bf16x8 vf1 = *(const bf16x8*)(vb_ + VADDR(1));                            \
        bf16x8 vf2 = *(const bf16x8*)(vb_ + VADDR(2));                            \
        bf16x8 vf3 = *(const bf16x8*)(vb_ + VADDR(3));                            \
        oacc0 = MFMA16(pf, vf0, oacc0);                                           \
        oacc1 = MFMA16(pf, vf1, oacc1);                                           \
        oacc2 = MFMA16(pf, vf2, oacc2);                                           \
        oacc3 = MFMA16(pf, vf3, oacc3);                                           \
    }

    // prologue
    STAGE2(0, 0)
    asm volatile("s_waitcnt vmcnt(0)" ::: "memory");
    __builtin_amdgcn_s_barrier();

    for (int t = 0; t < 32; ++t) {
        const int cur = t & 1;
        if (t > 0)  PSTORE(t - 1)         // stores FIRST (oldest in vm queue)
        if (t < 31) STAGE2(t + 1, cur ^ 1)
        TILE2(cur)
        asm volatile("s_waitcnt vmcnt(0)" ::: "memory");
        __builtin_amdgcn_s_barrier();
    }
    PSTORE(31)

    #undef TILE2
    #undef PSTORE
    #undef STAGE2
    #undef KADDR
    #undef VADDR

    // partial O -> osum (aliased over the staging buffers; staging is done)
    {
        float* osumW = (wave < 2 ? (float*)Kls : (float*)Vls) + (wave & 1) * (16 * OS_STRIDE);
        #pragma unroll
        for (int r = 0; r < 4; ++r) {
            const int prow = (quad << 2) + r;
            float* ow = osumW + prow * OS_STRIDE;
            ow[m16]      = oacc0[r];
            ow[16 + m16] = oacc1[r];
            ow[32 + m16] = oacc2[r];
            ow[48 + m16] = oacc3[r];
        }
    }
    __syncthreads();

    // combine key-halves + OUT store (gated rows only)
    #pragma unroll
    for (int rep = 0; rep < 8; ++rep) {
        const int idx = rep * 256 + tid;       // 0..2047
        const int row = idx >> 6;              // 0..31
        const int col = idx & 63;
        if ((gmask >> row) & 1u) {
            const float* base = (row < 16 ? (const float*)Kls : (const float*)Vls);
            const int r16 = row & 15;
            const float s = base[r16 * OS_STRIDE + col]
                          + base[16 * OS_STRIDE + r16 * OS_STRIDE + col];
            __builtin_nontemporal_store(
                s, &OUT[((size_t)(bh * LSEQ + q0 + row)) * DDIM + col]);
        }
    }

    // =================== window rows (gate off): exact fp32, 5-key softmax =========
    const int nw = 32 - g;
    for (int ii = wave; ii < nw; ii += 4) {
        const int row = sidx[g + ii];
        const int i   = q0 + row;
        const float qd = qb[row * DDIM + lane];

        float e[5];
        float denom = 0.f;
        #pragma unroll
        for (int jj = 0; jj < 5; ++jj) {
            const int  j  = i - 2 + jj;
            const bool ok = (j >= 0) && (j < LSEQ);
            const int  jc = ok ? j : 0;
            float tt = qd * K32[((size_t)bh * LSEQ + jc) * DDIM + lane];
            tt += __shfl_xor(tt, 1);  tt += __shfl_xor(tt, 2);
            tt += __shfl_xor(tt, 4);  tt += __shfl_xor(tt, 8);
            tt += __shfl_xor(tt, 16); tt += __shfl_xor(tt, 32);
            const float ee = ok ? __expf(tt * 0.125f) : 0.f;
            e[jj] = ee;
            denom += ee;
        }
        const float invd = 1.f / denom;
        #pragma unroll
        for (int jj = 0; jj < 5; ++jj) e[jj] *= invd;

        float o = 0.f;
        #pragma unroll
        for (int jj = 0; jj < 5; ++jj) {
            const int  j  = i - 2 + jj;
            const int  jc = (j >= 0 && j < LSEQ) ? j : 0;
            o += e[jj] * V32[((size_t)bh * LSEQ + jc) * DDIM + lane];
        }
        __builtin_nontemporal_store(o, &OUT[((size_t)(bh * LSEQ + i)) * DDIM + lane]);

        float* ar = ATT + ((size_t)(bh * LSEQ + i)) * LSEQ;
        const int jlo = i - 2;
        #pragma unroll
        for (int it = 0; it < 8; ++it) {
            const int c = (it << 8) + (lane << 2);
            f32x4 z = {0.f, 0.f, 0.f, 0.f};
            if (c + 3 >= jlo && c <= jlo + 4) {
                #pragma unroll
                for (int t4 = 0; t4 < 4; ++t4)
                    z[t4] = pick5(c + t4 - jlo, e[0], e[1], e[2], e[3], e[4]);
            }
            __builtin_nontemporal_store(z, (f32x4*)(ar + c));
        }
    }
}

extern "C" void kernel_launch(void* const* d_in, const int* in_sizes, int n_in,
                              void* d_out, int out_size, void* d_ws, size_t ws_size,
                              hipStream_t stream) {
    const float* q  = (const float*)d_in[0];
    const float* k  = (const float*)d_in[1];
    const float* v  = (const float*)d_in[2];
    const float* gw = (const float*)d_in[3];
    const float* gb = (const float*)d_in[4];

    float* out  = (float*)d_out;                      // [32,2048,64]
    float* attn = out + (size_t)32 * 2048 * 64;       // [32,2048,2048]

    // workspace: Kb bf16 [32][2048][64] (8MB) + Vt bf16 [32][64][2048] (8MB)
    unsigned short* Kb = (unsigned short*)d_ws;
    unsigned short* Vt = Kb + (size_t)32 * 2048 * 64;

    dim3 block(256);
    dsa_prep<<<dim3(1024), block, 0, stream>>>(k, v, Kb, Vt);
    dsa_main<<<dim3(2048), block, 0, stream>>>(q, Kb, Vt, k, v, gw, gb, out, attn);
}